// Round 4
// baseline (240.405 us; speedup 1.0000x reference)
//
#include <hip/hip_runtime.h>
#include <math.h>

#define T_LEN   16384
#define NBATCH  8
#define CH      32
#define NBLK    6
#define TILE    256
#define HALO    63
#define NTHR    384
#define NTILES  64
#define HS      36            // h row stride in dwords (144 B, 16B-aligned)

// workspace layout (dwords)
#define WS_CONV 0             // [i6][tap3][nt4][hl2][lane64][dw4] = 36864
#define WS_SKIP 36864         // [i6][nt2][hl2][lane64][dw4]      = 6144
#define WS_FIN  43008         // [nt2][hl2][lane64][dw4]          = 1024
#define WS_LOG  44032         // 16 floats logits
#define WS_CNT  44048         // 1 uint completion counter
#define PREP_N  44032
#define PREP_TOT 44056        // PREP_N + 24 (logits + counter + pad)

typedef short short8 __attribute__((ext_vector_type(8)));
typedef float f32x4  __attribute__((ext_vector_type(4)));

union F8 { unsigned u[4]; short8 v; };

__device__ __forceinline__ unsigned bf16_rne(float x) {
    unsigned u = __float_as_uint(x);
    return (u + 0x7fffu + ((u >> 16) & 1u)) >> 16;
}
// packed (hi_bf16 << 16) | lo_bf16: rne hi, truncated lo, v_perm combine (~5 VALU)
__device__ __forceinline__ unsigned packbf_fast(float x) {
    unsigned u  = __float_as_uint(x);
    unsigned ub = u + 0x7fffu + ((u >> 16) & 1u);
    float hif   = __uint_as_float(ub & 0xffff0000u);
    unsigned lo = __float_as_uint(x - hif);
    return __builtin_amdgcn_perm(ub, lo, 0x07060302u);
}
__device__ __forceinline__ float uph(unsigned p) { return __uint_as_float(p & 0xffff0000u); }
__device__ __forceinline__ float upl(unsigned p) { return __uint_as_float(p << 16); }

__device__ __forceinline__ short8 mkhi(uint4 q0, uint4 q1) {
    F8 r;
    r.u[0] = __builtin_amdgcn_perm(q0.y, q0.x, 0x07060302u);
    r.u[1] = __builtin_amdgcn_perm(q0.w, q0.z, 0x07060302u);
    r.u[2] = __builtin_amdgcn_perm(q1.y, q1.x, 0x07060302u);
    r.u[3] = __builtin_amdgcn_perm(q1.w, q1.z, 0x07060302u);
    return r.v;
}
__device__ __forceinline__ short8 mklo(uint4 q0, uint4 q1) {
    F8 r;
    r.u[0] = __builtin_amdgcn_perm(q0.y, q0.x, 0x05040100u);
    r.u[1] = __builtin_amdgcn_perm(q0.w, q0.z, 0x05040100u);
    r.u[2] = __builtin_amdgcn_perm(q1.y, q1.x, 0x05040100u);
    r.u[3] = __builtin_amdgcn_perm(q1.w, q1.z, 0x05040100u);
    return r.v;
}

__device__ __forceinline__ float sig_fast(float x) {
    return __builtin_amdgcn_rcpf(1.0f + __expf(-x));
}
__device__ __forceinline__ float tanh_fast(float x) {
    return fmaf(2.0f, sig_fast(2.0f * x), -1.0f);
}
__device__ __forceinline__ float relu(float x) { return fmaxf(x, 0.0f); }

#define MFMA(a, b, c) __builtin_amdgcn_mfma_f32_16x16x32_bf16((a), (b), (c), 0, 0, 0)

// ---------------- weight prep: fp32 -> bf16 hi/lo B-fragments + zero logits/counter ----
__device__ __forceinline__ unsigned cvt16(float v, int hl) {
    unsigned hi = bf16_rne(v);
    if (hl == 0) return hi;
    return bf16_rne(v - __uint_as_float(hi << 16));
}

__global__ void wavenet_prep(const float* __restrict__ wt, const float* __restrict__ wsg,
                             const float* __restrict__ wsk, const float* __restrict__ wfin,
                             unsigned* __restrict__ out)
{
    int id = blockIdx.x * 256 + threadIdx.x;
    if (id >= PREP_TOT) return;
    if (id >= PREP_N) { out[id] = 0u; return; }   // zero logits + counter
    int dw = id & 3, lane = (id >> 2) & 63;
    int g = lane >> 4, nlo = lane & 15;
    int e0 = dw * 2, e1 = dw * 2 + 1;
    float v0, v1; int hl;
    if (id < WS_SKIP) {
        hl = (id >> 8) & 1; int nt = (id >> 9) & 3; int q = id >> 11;
        int tap = q % 3, i = q / 3;
        int n = nt * 16 + nlo;
        const float* src = (n < 32) ? wt : wsg;
        int nn = (n < 32) ? n : n - 32;
        v0 = src[(((i * 3 + tap) * 32) + g * 8 + e0) * 32 + nn];
        v1 = src[(((i * 3 + tap) * 32) + g * 8 + e1) * 32 + nn];
    } else if (id < WS_FIN) {
        int t = id - WS_SKIP;
        hl = (t >> 8) & 1; int nt = (t >> 9) & 1; int i = t >> 10;
        int n = nt * 16 + nlo;
        v0 = wsk[((i * 32) + g * 8 + e0) * 32 + n];
        v1 = wsk[((i * 32) + g * 8 + e1) * 32 + n];
    } else {
        int t = id - WS_FIN;
        hl = (t >> 8) & 1; int nt = (t >> 9) & 1;
        int n = nt * 16 + nlo;
        v0 = wfin[(g * 8 + e0) * 32 + n];
        v1 = wfin[(g * 8 + e1) * 32 + n];
    }
    out[id] = (cvt16(v1, hl) << 16) | cvt16(v0, hl);
}

// ---------------- main fused kernel ----------------
__global__ __launch_bounds__(NTHR, 3)
void wavenet_main(const float* __restrict__ x,
                  const float* __restrict__ w_init, const float* __restrict__ b_init,
                  const float* __restrict__ b_tanh, const float* __restrict__ b_sig,
                  const float* __restrict__ b_skip, const float* __restrict__ b_final,
                  const float* __restrict__ b_dense,
                  const float* __restrict__ w_dense,
                  const unsigned* __restrict__ wsB,
                  float* __restrict__ logits, unsigned* __restrict__ counter,
                  float* __restrict__ out)
{
    __shared__ unsigned h_pack[NTHR * HS];     // 55296 B
    __shared__ unsigned z_pack[6 * 16 * HS];   // 13824 B
    __shared__ float x_s[NTHR];                // 1536 B
    __shared__ float red[6][2];

    const int tid  = threadIdx.x;
    const int lane = tid & 63;
    const int wv   = tid >> 6;
    const int tile = blockIdx.x & (NTILES - 1);
    const int b    = blockIdx.x >> 6;
    const int col0 = lane & 15;
    const int g4   = lane >> 4;

    const float wi0 = w_init[col0],      wi1 = w_init[col0 + 16];
    const float bi0 = b_init[col0],      bi1 = b_init[col0 + 16];

    // ---- init conv (CIN=1) -> packed hi/lo h in LDS ----
    {
        int j = tid;
        int tg = tile * TILE - HALO + j;
        bool valid = (tg >= 0) && (tg < T_LEN);
        float xv = valid ? x[(size_t)b * T_LEN + tg] : 0.0f;
        x_s[j] = xv;
        unsigned* hp = &h_pack[j * HS];
        #pragma unroll
        for (int q = 0; q < 8; ++q) {
            uint4 pk;
            pk.x = valid ? packbf_fast(relu(fmaf(xv, w_init[4 * q + 0], b_init[4 * q + 0]))) : 0u;
            pk.y = valid ? packbf_fast(relu(fmaf(xv, w_init[4 * q + 1], b_init[4 * q + 1]))) : 0u;
            pk.z = valid ? packbf_fast(relu(fmaf(xv, w_init[4 * q + 2], b_init[4 * q + 2]))) : 0u;
            pk.w = valid ? packbf_fast(relu(fmaf(xv, w_init[4 * q + 3], b_init[4 * q + 3]))) : 0u;
            *(uint4*)(hp + 4 * q) = pk;
        }
    }

    unsigned* zb = &z_pack[wv * 16 * HS];

    for (int i = 0; i < NBLK; ++i) {
        const int d = 1 << i;
        __syncthreads();   // prev iter's h writes (or init) visible

        // skip-conv B-frags + biases in flight early
        short8 skh[2], skl[2];
        #pragma unroll
        for (int nt = 0; nt < 2; ++nt) {
            const unsigned* bp = wsB + WS_SKIP + ((i * 2 + nt) * 2) * 256 + lane * 4;
            skh[nt] = *(const short8*)bp;
            skl[nt] = *(const short8*)(bp + 256);
        }
        float bt0 = b_tanh[i * 32 + col0], bt1 = b_tanh[i * 32 + col0 + 16];
        float bs0 = b_sig [i * 32 + col0], bs1 = b_sig [i * 32 + col0 + 16];
        float bk0 = b_skip[i * 32 + col0], bk1 = b_skip[i * 32 + col0 + 16];

        f32x4 acc[4][4];
        #pragma unroll
        for (int mt = 0; mt < 4; ++mt)
            #pragma unroll
            for (int nt = 0; nt < 4; ++nt) acc[mt][nt] = (f32x4){0.f, 0.f, 0.f, 0.f};

        // conv GEMM: [384 x 96] x [96 x 64]  (bf16 hi/lo, 3-product split)
        #pragma unroll
        for (int tap = 0; tap < 3; ++tap) {
            short8 bh[4], bl[4];
            #pragma unroll
            for (int nt = 0; nt < 4; ++nt) {
                const unsigned* bp = wsB + (((i * 3 + tap) * 4 + nt) * 2) * 256 + lane * 4;
                bh[nt] = *(const short8*)bp;
                bl[nt] = *(const short8*)(bp + 256);
            }
            int rb = wv * 64 + (tap - 1) * d + col0;
            #pragma unroll
            for (int mt = 0; mt < 4; ++mt) {
                int r = rb + 16 * mt;
                r = r < 0 ? 0 : (r > NTHR - 1 ? NTHR - 1 : r);
                const unsigned* hp = &h_pack[r * HS + g4 * 8];
                uint4 q0 = *(const uint4*)hp;
                uint4 q1 = *(const uint4*)(hp + 4);
                short8 ah = mkhi(q0, q1), al = mklo(q0, q1);
                #pragma unroll
                for (int nt = 0; nt < 4; ++nt) {
                    acc[mt][nt] = MFMA(ah, bh[nt], acc[mt][nt]);
                    acc[mt][nt] = MFMA(ah, bl[nt], acc[mt][nt]);
                    acc[mt][nt] = MFMA(al, bh[nt], acc[mt][nt]);
                }
            }
        }

        // ---- phase 1 (pre-barrier): gated activation -> z LDS round trip, all 4 mt.
        // LDS pipe is in-order per wave: read(mt) sees write(mt) and is immune to
        // the mt+1 clobber of the same 16-row buffer; no explicit waitcnt needed.
        uint4 zA[4][2];
        #pragma unroll
        for (int mt = 0; mt < 4; ++mt) {
            #pragma unroll
            for (int reg = 0; reg < 4; ++reg) {
                float z0 = tanh_fast(acc[mt][0][reg] + bt0) * sig_fast(acc[mt][2][reg] + bs0);
                float z1 = tanh_fast(acc[mt][1][reg] + bt1) * sig_fast(acc[mt][3][reg] + bs1);
                unsigned* zp = zb + (4 * g4 + reg) * HS + col0;
                zp[0]  = packbf_fast(z0);
                zp[16] = packbf_fast(z1);
            }
            const unsigned* za = zb + col0 * HS + g4 * 8;
            zA[mt][0] = *(const uint4*)za;
            zA[mt][1] = *(const uint4*)(za + 4);
        }

        __syncthreads();   // all conv reads of h done (h writes below are safe)

        // ---- phase 2: skip MFMAs + residual h update (telescope: skip_sum = h6 - h0)
        #pragma unroll
        for (int mt = 0; mt < 4; ++mt) {
            short8 azh = mkhi(zA[mt][0], zA[mt][1]), azl = mklo(zA[mt][0], zA[mt][1]);
            f32x4 s0 = (f32x4){0.f, 0.f, 0.f, 0.f}, s1 = (f32x4){0.f, 0.f, 0.f, 0.f};
            s0 = MFMA(azh, skh[0], s0); s0 = MFMA(azh, skl[0], s0); s0 = MFMA(azl, skh[0], s0);
            s1 = MFMA(azh, skh[1], s1); s1 = MFMA(azh, skl[1], s1); s1 = MFMA(azl, skh[1], s1);
            #pragma unroll
            for (int reg = 0; reg < 4; ++reg) {
                int row = wv * 64 + 16 * mt + 4 * g4 + reg;
                int tgr = tile * TILE - HALO + row;
                bool vr = (tgr >= 0) && (tgr < T_LEN);
                float sk0 = relu(s0[reg] + bk0);
                float sk1 = relu(s1[reg] + bk1);
                unsigned* hp2 = &h_pack[row * HS + col0];
                unsigned p0 = hp2[0], p1 = hp2[16];
                float h0n = sk0 + uph(p0) + upl(p0);
                float h1n = sk1 + uph(p1) + upl(p1);
                if (i != NBLK - 1) {
                    hp2[0]  = vr ? packbf_fast(h0n) : 0u;
                    hp2[16] = vr ? packbf_fast(h1n) : 0u;
                } else {
                    float xr  = x_s[row];
                    float hi0 = relu(fmaf(xr, wi0, bi0));
                    float hi1 = relu(fmaf(xr, wi1, bi1));
                    hp2[0]  = packbf_fast(relu(h0n - hi0));
                    hp2[16] = packbf_fast(relu(h1n - hi1));
                }
            }
        }
    }

    // ---- final 1x1 conv via MFMA on y (wave-local rows: in-order LDS, no barrier) ----
    short8 fh[2], fl[2];
    #pragma unroll
    for (int nt = 0; nt < 2; ++nt) {
        const unsigned* bp = wsB + WS_FIN + (nt * 2) * 256 + lane * 4;
        fh[nt] = *(const short8*)bp;
        fl[nt] = *(const short8*)(bp + 256);
    }
    float bf0 = b_final[col0], bf1 = b_final[col0 + 16];
    float pa = 0.0f, pb = 0.0f;

    #pragma unroll
    for (int mt = 0; mt < 4; ++mt) {
        const unsigned* ya = &h_pack[(wv * 64 + 16 * mt + col0) * HS + g4 * 8];
        uint4 yq0 = *(const uint4*)ya;
        uint4 yq1 = *(const uint4*)(ya + 4);
        short8 ayh = mkhi(yq0, yq1), ayl = mklo(yq0, yq1);
        f32x4 f0 = (f32x4){0.f, 0.f, 0.f, 0.f}, f1 = (f32x4){0.f, 0.f, 0.f, 0.f};
        f0 = MFMA(ayh, fh[0], f0); f0 = MFMA(ayh, fl[0], f0); f0 = MFMA(ayl, fh[0], f0);
        f1 = MFMA(ayh, fh[1], f1); f1 = MFMA(ayh, fl[1], f1); f1 = MFMA(ayl, fh[1], f1);
        #pragma unroll
        for (int reg = 0; reg < 4; ++reg) {
            int row = wv * 64 + 16 * mt + 4 * g4 + reg;
            if (row >= HALO && row < HALO + TILE) {
                int tgr = tile * TILE - HALO + row;
                float v0 = relu(f0[reg] + bf0);
                float v1 = relu(f1[reg] + bf1);
                const float* wd0 = w_dense + ((size_t)tgr * 32 + col0) * 2;
                const float* wd1 = w_dense + ((size_t)tgr * 32 + col0 + 16) * 2;
                pa = fmaf(v0, wd0[0], pa); pb = fmaf(v0, wd0[1], pb);
                pa = fmaf(v1, wd1[0], pa); pb = fmaf(v1, wd1[1], pb);
            }
        }
    }

    // block reduction -> logits; last-arriving block does the softmax
    #pragma unroll
    for (int off = 32; off > 0; off >>= 1) {
        pa += __shfl_down(pa, off);
        pb += __shfl_down(pb, off);
    }
    if (lane == 0) { red[wv][0] = pa; red[wv][1] = pb; }
    __syncthreads();
    if (tid == 0) {
        float s0 = 0.0f, s1 = 0.0f;
        #pragma unroll
        for (int w = 0; w < 6; ++w) { s0 += red[w][0]; s1 += red[w][1]; }
        atomicAdd(&logits[b * 2 + 0], s0);
        atomicAdd(&logits[b * 2 + 1], s1);
        __threadfence();
        unsigned arrived = atomicAdd(counter, 1u);
        if (arrived == (unsigned)(NBATCH * NTILES - 1)) {
            __threadfence();
            float bd0 = b_dense[0], bd1 = b_dense[1];
            for (int bb = 0; bb < NBATCH; ++bb) {
                float l0 = atomicAdd(&logits[bb * 2 + 0], 0.0f) + bd0;
                float l1 = atomicAdd(&logits[bb * 2 + 1], 0.0f) + bd1;
                float m  = fmaxf(l0, l1);
                float e0 = __expf(l0 - m), e1 = __expf(l1 - m);
                float inv = __builtin_amdgcn_rcpf(e0 + e1);
                out[bb * 2 + 0] = e0 * inv;
                out[bb * 2 + 1] = e1 * inv;
            }
        }
    }
}

extern "C" void kernel_launch(void* const* d_in, const int* in_sizes, int n_in,
                              void* d_out, int out_size, void* d_ws, size_t ws_size,
                              hipStream_t stream) {
    const float* x       = (const float*)d_in[0];
    const float* w_init  = (const float*)d_in[1];
    const float* b_init  = (const float*)d_in[2];
    const float* w_tanh  = (const float*)d_in[3];
    const float* b_tanh  = (const float*)d_in[4];
    const float* w_sig   = (const float*)d_in[5];
    const float* b_sig   = (const float*)d_in[6];
    const float* w_skip  = (const float*)d_in[7];
    const float* b_skip  = (const float*)d_in[8];
    const float* w_final = (const float*)d_in[9];
    const float* b_final = (const float*)d_in[10];
    const float* w_dense = (const float*)d_in[11];
    const float* b_dense = (const float*)d_in[12];

    unsigned* wsB     = (unsigned*)d_ws;
    float*    logits  = (float*)d_ws + WS_LOG;
    unsigned* counter = (unsigned*)d_ws + WS_CNT;

    wavenet_prep<<<(PREP_TOT + 255) / 256, 256, 0, stream>>>(w_tanh, w_sig, w_skip, w_final, wsB);
    wavenet_main<<<NBATCH * NTILES, NTHR, 0, stream>>>(
        x, w_init, b_init, b_tanh, b_sig, b_skip, b_final, b_dense, w_dense,
        wsB, logits, counter, (float*)d_out);
}

// Round 5
// 208.419 us; speedup vs baseline: 1.1535x; 1.1535x over previous
//
#include <hip/hip_runtime.h>
#include <math.h>

#define T_LEN   16384
#define NBATCH  8
#define CH      32
#define NBLK    6
#define TILE    256
#define HALO    63
#define NTHR    384
#define NTILES  64
#define HS      36            // row stride in dwords: [16 hi-plane][16 lo-plane][4 pad]

// workspace layout (dwords)
#define WS_CONV 0             // [i6][tap3][nt4][hl2][lane64][dw4] = 36864
#define WS_SKIP 36864         // [i6][nt2][hl2][lane64][dw4]      = 6144
#define WS_FIN  43008         // [nt2][hl2][lane64][dw4]          = 1024
#define WS_LOG  44032         // 16 floats logits
#define WS_CNT  44048         // 1 uint completion counter
#define PREP_N  44032
#define PREP_TOT 44056

typedef short short8 __attribute__((ext_vector_type(8)));
typedef float f32x4  __attribute__((ext_vector_type(4)));

__device__ __forceinline__ unsigned rne_hi_bits(float x) {
    unsigned u = __float_as_uint(x);
    return u + 0x7fffu + ((u >> 16) & 1u);   // bf16(rne) in bits [31:16]
}
// pack adjacent-channel pair (f0=even chan, f1=odd chan) into hi-plane dword
// (bf16(f1)<<16 | bf16(f0)) and lo-plane dword (truncated residuals).
__device__ __forceinline__ void pack2(float f0, float f1, unsigned& hid, unsigned& lod) {
    unsigned ub0 = rne_hi_bits(f0), ub1 = rne_hi_bits(f1);
    float hif0 = __uint_as_float(ub0 & 0xffff0000u);
    float hif1 = __uint_as_float(ub1 & 0xffff0000u);
    unsigned l0 = __float_as_uint(f0 - hif0);
    unsigned l1 = __float_as_uint(f1 - hif1);
    hid = __builtin_amdgcn_perm(ub1, ub0, 0x07060302u);
    lod = __builtin_amdgcn_perm(l1, l0, 0x07060302u);
}

__device__ __forceinline__ float sig_fast(float x) {
    return __builtin_amdgcn_rcpf(1.0f + __expf(-x));
}
__device__ __forceinline__ float tanh_fast(float x) {
    return fmaf(2.0f, sig_fast(2.0f * x), -1.0f);
}
__device__ __forceinline__ float relu(float x) { return fmaxf(x, 0.0f); }

#define MFMA(a, b, c) __builtin_amdgcn_mfma_f32_16x16x32_bf16((a), (b), (c), 0, 0, 0)

// ---------------- weight prep: fp32 -> bf16 hi/lo B-fragments (permuted cols) ----
// Column permutation: matrix col n = nt*16+nlo holds channel 2*nlo + (nt&1)
// (conv: nt 0..1 = tanh, nt 2..3 = sig). So C-layout lane col0 owns adjacent
// channels 2*col0, 2*col0+1 -> hi/lo-plane LDS layout, perm-free A-fragments.
__device__ __forceinline__ unsigned cvt16(float v, int hl) {
    unsigned hi = rne_hi_bits(v) >> 16;
    if (hl == 0) return hi;
    return rne_hi_bits(v - __uint_as_float(hi << 16)) >> 16;
}

__global__ void wavenet_prep(const float* __restrict__ wt, const float* __restrict__ wsg,
                             const float* __restrict__ wsk, const float* __restrict__ wfin,
                             unsigned* __restrict__ out)
{
    int id = blockIdx.x * 256 + threadIdx.x;
    if (id >= PREP_TOT) return;
    if (id >= PREP_N) { out[id] = 0u; return; }   // zero logits + counter
    int dw = id & 3, lane = (id >> 2) & 63;
    int g = lane >> 4, nlo = lane & 15;
    int k0 = g * 8 + dw * 2, k1 = k0 + 1;
    float v0, v1; int hl;
    if (id < WS_SKIP) {
        hl = (id >> 8) & 1; int nt = (id >> 9) & 3; int q = id >> 11;
        int tap = q % 3, i = q / 3;
        int chan = 2 * nlo + (nt & 1);
        const float* src = (nt < 2) ? wt : wsg;
        v0 = src[((i * 3 + tap) * 32 + k0) * 32 + chan];
        v1 = src[((i * 3 + tap) * 32 + k1) * 32 + chan];
    } else if (id < WS_FIN) {
        int t = id - WS_SKIP;
        hl = (t >> 8) & 1; int nt = (t >> 9) & 1; int i = t >> 10;
        int chan = 2 * nlo + nt;
        v0 = wsk[(i * 32 + k0) * 32 + chan];
        v1 = wsk[(i * 32 + k1) * 32 + chan];
    } else {
        int t = id - WS_FIN;
        hl = (t >> 8) & 1; int nt = (t >> 9) & 1;
        int chan = 2 * nlo + nt;
        v0 = wfin[k0 * 32 + chan];
        v1 = wfin[k1 * 32 + chan];
    }
    out[id] = (cvt16(v1, hl) << 16) | cvt16(v0, hl);
}

// ---------------- main fused kernel ----------------
__global__ __launch_bounds__(NTHR, 3)
void wavenet_main(const float* __restrict__ x,
                  const float* __restrict__ w_init, const float* __restrict__ b_init,
                  const float* __restrict__ b_tanh, const float* __restrict__ b_sig,
                  const float* __restrict__ b_skip, const float* __restrict__ b_final,
                  const float* __restrict__ b_dense,
                  const float* __restrict__ w_dense,
                  const unsigned* __restrict__ wsB,
                  float* __restrict__ logits, unsigned* __restrict__ counter,
                  float* __restrict__ out)
{
    __shared__ unsigned h_pack[NTHR * HS];     // 55296 B
    __shared__ unsigned z_pack[6 * 16 * HS];   // 13824 B
    __shared__ float x_s[NTHR];                // 1536 B
    __shared__ float red[6][2];

    const int tid  = threadIdx.x;
    const int lane = tid & 63;
    const int wv   = tid >> 6;
    const int tile = blockIdx.x & (NTILES - 1);
    const int b    = blockIdx.x >> 6;
    const int col0 = lane & 15;
    const int g4   = lane >> 4;

    const float wi0 = w_init[2 * col0], wi1 = w_init[2 * col0 + 1];
    const float bi0 = b_init[2 * col0], bi1 = b_init[2 * col0 + 1];

    // ---- init conv (CIN=1) -> hi/lo-plane h in LDS ----
    {
        int j = tid;
        int tg = tile * TILE - HALO + j;
        bool valid = (tg >= 0) && (tg < T_LEN);
        float xv = valid ? x[(size_t)b * T_LEN + tg] : 0.0f;
        x_s[j] = xv;
        unsigned* hp = &h_pack[j * HS];
        #pragma unroll
        for (int qq = 0; qq < 4; ++qq) {
            uint4 hv, lv;
            unsigned hd, ld;
            #define INITQ(e, fx, fy) { \
                int q = 4 * qq + e; \
                float f0 = relu(fmaf(xv, w_init[2 * q],     b_init[2 * q])); \
                float f1 = relu(fmaf(xv, w_init[2 * q + 1], b_init[2 * q + 1])); \
                pack2(f0, f1, hd, ld); \
                fx = valid ? hd : 0u; fy = valid ? ld : 0u; }
            INITQ(0, hv.x, lv.x) INITQ(1, hv.y, lv.y)
            INITQ(2, hv.z, lv.z) INITQ(3, hv.w, lv.w)
            #undef INITQ
            *(uint4*)(hp + 4 * qq)      = hv;
            *(uint4*)(hp + 16 + 4 * qq) = lv;
        }
    }

    unsigned* zb = &z_pack[wv * 16 * HS];

    for (int i = 0; i < NBLK; ++i) {
        const int d = 1 << i;
        __syncthreads();   // init / prev iter's h writes visible

        f32x4 acc[4][4];
        #pragma unroll
        for (int mt = 0; mt < 4; ++mt)
            #pragma unroll
            for (int nt = 0; nt < 4; ++nt) acc[mt][nt] = (f32x4){0.f, 0.f, 0.f, 0.f};

        // conv GEMM: [384 x 96] x [96 x 64]  (bf16 hi/lo, 3-product split)
        #pragma unroll
        for (int tap = 0; tap < 3; ++tap) {
            short8 bh[4], bl[4];
            #pragma unroll
            for (int nt = 0; nt < 4; ++nt) {
                const unsigned* bp = wsB + (((i * 3 + tap) * 4 + nt) * 2) * 256 + lane * 4;
                bh[nt] = *(const short8*)bp;
                bl[nt] = *(const short8*)(bp + 256);
            }
            int rb = wv * 64 + (tap - 1) * d + col0;
            #pragma unroll
            for (int mt = 0; mt < 4; ++mt) {
                int r = rb + 16 * mt;
                r = r < 0 ? 0 : (r > NTHR - 1 ? NTHR - 1 : r);
                const unsigned* hp = &h_pack[r * HS];
                short8 ah = *(const short8*)(hp + g4 * 4);        // hi-plane, perm-free
                short8 al = *(const short8*)(hp + 16 + g4 * 4);   // lo-plane
                #pragma unroll
                for (int nt = 0; nt < 4; ++nt) {
                    acc[mt][nt] = MFMA(ah, bh[nt], acc[mt][nt]);
                    acc[mt][nt] = MFMA(ah, bl[nt], acc[mt][nt]);
                    acc[mt][nt] = MFMA(al, bh[nt], acc[mt][nt]);
                }
            }
        }

        __syncthreads();   // all conv reads of h done; h writes below are safe

        // skip-conv B-frags + biases (post-conv: keeps conv-phase live set small)
        short8 skh[2], skl[2];
        #pragma unroll
        for (int nt = 0; nt < 2; ++nt) {
            const unsigned* bp = wsB + WS_SKIP + ((i * 2 + nt) * 2) * 256 + lane * 4;
            skh[nt] = *(const short8*)bp;
            skl[nt] = *(const short8*)(bp + 256);
        }
        float2 btv = *(const float2*)&b_tanh[i * 32 + 2 * col0];
        float2 bsv = *(const float2*)&b_sig [i * 32 + 2 * col0];
        float2 bkv = *(const float2*)&b_skip[i * 32 + 2 * col0];

        #pragma unroll
        for (int mt = 0; mt < 4; ++mt) {
            // gated activation -> z (hi/lo planes) into wave-local LDS
            #pragma unroll
            for (int reg = 0; reg < 4; ++reg) {
                float z0 = tanh_fast(acc[mt][0][reg] + btv.x) * sig_fast(acc[mt][2][reg] + bsv.x);
                float z1 = tanh_fast(acc[mt][1][reg] + btv.y) * sig_fast(acc[mt][3][reg] + bsv.y);
                unsigned hd, ld; pack2(z0, z1, hd, ld);
                unsigned* zp = zb + (4 * g4 + reg) * HS + col0;
                zp[0]  = hd;
                zp[16] = ld;
            }
            asm volatile("s_waitcnt lgkmcnt(0)" ::: "memory");
            // z as A-fragments (wave-local; in-order DS pipe protects mt-reuse)
            const unsigned* za = zb + col0 * HS;
            short8 azh = *(const short8*)(za + g4 * 4);
            short8 azl = *(const short8*)(za + 16 + g4 * 4);
            f32x4 s0 = (f32x4){0.f, 0.f, 0.f, 0.f}, s1 = (f32x4){0.f, 0.f, 0.f, 0.f};
            s0 = MFMA(azh, skh[0], s0); s0 = MFMA(azh, skl[0], s0); s0 = MFMA(azl, skh[0], s0);
            s1 = MFMA(azh, skh[1], s1); s1 = MFMA(azh, skl[1], s1); s1 = MFMA(azl, skh[1], s1);
            // skip epilogue + residual (telescope: skip_sum = h6 - h0)
            #pragma unroll
            for (int reg = 0; reg < 4; ++reg) {
                int row = wv * 64 + 16 * mt + 4 * g4 + reg;
                int tgr = tile * TILE - HALO + row;
                bool vr = (tgr >= 0) && (tgr < T_LEN);
                float sk0 = relu(s0[reg] + bkv.x);
                float sk1 = relu(s1[reg] + bkv.y);
                unsigned* hp2 = &h_pack[row * HS + col0];
                unsigned ph = hp2[0], pl = hp2[16];
                float h0n = sk0 + __uint_as_float(ph << 16) + __uint_as_float(pl << 16);
                float h1n = sk1 + __uint_as_float(ph & 0xffff0000u) + __uint_as_float(pl & 0xffff0000u);
                unsigned hd, ld;
                if (i != NBLK - 1) {
                    pack2(vr ? h0n : 0.0f, vr ? h1n : 0.0f, hd, ld);
                } else {
                    float xr  = x_s[row];
                    float hi0 = relu(fmaf(xr, wi0, bi0));
                    float hi1 = relu(fmaf(xr, wi1, bi1));
                    pack2(relu(h0n - hi0), relu(h1n - hi1), hd, ld);
                }
                hp2[0]  = hd;
                hp2[16] = ld;
            }
        }
    }

    // ---- final 1x1 conv via MFMA on y (own-wave rows; in-order DS, drain first) ----
    asm volatile("s_waitcnt lgkmcnt(0)" ::: "memory");
    short8 fh[2], fl[2];
    #pragma unroll
    for (int nt = 0; nt < 2; ++nt) {
        const unsigned* bp = wsB + WS_FIN + (nt * 2) * 256 + lane * 4;
        fh[nt] = *(const short8*)bp;
        fl[nt] = *(const short8*)(bp + 256);
    }
    float2 bfv = *(const float2*)&b_final[2 * col0];
    float pa = 0.0f, pb = 0.0f;

    #pragma unroll
    for (int mt = 0; mt < 4; ++mt) {
        const unsigned* ya = &h_pack[(wv * 64 + 16 * mt + col0) * HS];
        short8 ayh = *(const short8*)(ya + g4 * 4);
        short8 ayl = *(const short8*)(ya + 16 + g4 * 4);
        f32x4 f0 = (f32x4){0.f, 0.f, 0.f, 0.f}, f1 = (f32x4){0.f, 0.f, 0.f, 0.f};
        f0 = MFMA(ayh, fh[0], f0); f0 = MFMA(ayh, fl[0], f0); f0 = MFMA(ayl, fh[0], f0);
        f1 = MFMA(ayh, fh[1], f1); f1 = MFMA(ayh, fl[1], f1); f1 = MFMA(ayl, fh[1], f1);
        #pragma unroll
        for (int reg = 0; reg < 4; ++reg) {
            int row = wv * 64 + 16 * mt + 4 * g4 + reg;
            if (row >= HALO && row < HALO + TILE) {
                int tgr = tile * TILE - HALO + row;
                float v0 = relu(f0[reg] + bfv.x);
                float v1 = relu(f1[reg] + bfv.y);
                float4 wd = *(const float4*)&w_dense[((size_t)tgr * 32 + 2 * col0) * 2];
                pa = fmaf(v0, wd.x, pa); pb = fmaf(v0, wd.y, pb);
                pa = fmaf(v1, wd.z, pa); pb = fmaf(v1, wd.w, pb);
            }
        }
    }

    // block reduction -> logits; last-arriving block does the softmax
    #pragma unroll
    for (int off = 32; off > 0; off >>= 1) {
        pa += __shfl_down(pa, off);
        pb += __shfl_down(pb, off);
    }
    if (lane == 0) { red[wv][0] = pa; red[wv][1] = pb; }
    __syncthreads();
    if (tid == 0) {
        float s0 = 0.0f, s1 = 0.0f;
        #pragma unroll
        for (int w = 0; w < 6; ++w) { s0 += red[w][0]; s1 += red[w][1]; }
        atomicAdd(&logits[b * 2 + 0], s0);
        atomicAdd(&logits[b * 2 + 1], s1);
        __threadfence();
        unsigned arrived = atomicAdd(counter, 1u);
        if (arrived == (unsigned)(NBATCH * NTILES - 1)) {
            __threadfence();
            float bd0 = b_dense[0], bd1 = b_dense[1];
            for (int bb = 0; bb < NBATCH; ++bb) {
                float l0 = atomicAdd(&logits[bb * 2 + 0], 0.0f) + bd0;
                float l1 = atomicAdd(&logits[bb * 2 + 1], 0.0f) + bd1;
                float m  = fmaxf(l0, l1);
                float e0 = __expf(l0 - m), e1 = __expf(l1 - m);
                float inv = __builtin_amdgcn_rcpf(e0 + e1);
                out[bb * 2 + 0] = e0 * inv;
                out[bb * 2 + 1] = e1 * inv;
            }
        }
    }
}

extern "C" void kernel_launch(void* const* d_in, const int* in_sizes, int n_in,
                              void* d_out, int out_size, void* d_ws, size_t ws_size,
                              hipStream_t stream) {
    const float* x       = (const float*)d_in[0];
    const float* w_init  = (const float*)d_in[1];
    const float* b_init  = (const float*)d_in[2];
    const float* w_tanh  = (const float*)d_in[3];
    const float* b_tanh  = (const float*)d_in[4];
    const float* w_sig   = (const float*)d_in[5];
    const float* b_sig   = (const float*)d_in[6];
    const float* w_skip  = (const float*)d_in[7];
    const float* b_skip  = (const float*)d_in[8];
    const float* w_final = (const float*)d_in[9];
    const float* b_final = (const float*)d_in[10];
    const float* w_dense = (const float*)d_in[11];
    const float* b_dense = (const float*)d_in[12];

    unsigned* wsB     = (unsigned*)d_ws;
    float*    logits  = (float*)d_ws + WS_LOG;
    unsigned* counter = (unsigned*)d_ws + WS_CNT;

    wavenet_prep<<<(PREP_TOT + 255) / 256, 256, 0, stream>>>(w_tanh, w_sig, w_skip, w_final, wsB);
    wavenet_main<<<NBATCH * NTILES, NTHR, 0, stream>>>(
        x, w_init, b_init, b_tanh, b_sig, b_skip, b_final, b_dense, w_dense,
        wsB, logits, counter, (float*)d_out);
}

// Round 6
// 167.682 us; speedup vs baseline: 1.4337x; 1.2429x over previous
//
#include <hip/hip_runtime.h>
#include <math.h>

#define T_LEN   16384
#define NBATCH  8
#define NBLK    6
#define TILE    256
#define HALO    63
#define NTHR    384
#define NTILES  64
#define HS      18            // f16 row stride in dwords (72 B, 8B-aligned, stride-18 banks)
#define HBUF    (NTHR * HS)   // one h buffer in dwords

// workspace layout (dwords)
#define WS_CONV 0             // [i6][tap3][nt4][lane64][dw4] = 18432
#define WS_SKIP 18432         // [i6][nt2][lane64][dw4]      = 3072
#define WS_FIN  21504         // [nt2][lane64][dw4]          = 512
#define WS_LOG  22016         // 16 floats logits
#define WS_CNT  22032         // 1 uint completion counter
#define PREP_N  22016
#define PREP_TOT 22036

typedef _Float16 half8 __attribute__((ext_vector_type(8)));
typedef float f32x4  __attribute__((ext_vector_type(4)));

union HPK { unsigned u; _Float16 h[2]; };
union AFR { uint2 u2[2]; half8 v; };

__device__ __forceinline__ unsigned packh(float a, float b) {   // 2x v_cvt_f16_f32 (RNE) + pack
    HPK r; r.h[0] = (_Float16)a; r.h[1] = (_Float16)b; return r.u;
}
__device__ __forceinline__ float f16a(unsigned p) { HPK r; r.u = p; return (float)r.h[0]; }
__device__ __forceinline__ float f16b(unsigned p) { HPK r; r.u = p; return (float)r.h[1]; }

__device__ __forceinline__ float sig_fast(float x) {
    return __builtin_amdgcn_rcpf(1.0f + __expf(-x));
}
__device__ __forceinline__ float tanh_fast(float x) {
    return fmaf(2.0f, sig_fast(2.0f * x), -1.0f);
}
__device__ __forceinline__ float relu(float x) { return fmaxf(x, 0.0f); }

#define MFMA(a, b, c) __builtin_amdgcn_mfma_f32_16x16x32_f16((a), (b), (c), 0, 0, 0)

// ---------------- weight prep: fp32 -> f16 B-fragments (permuted cols) ----------------
// matrix col n = nt*16+nlo holds channel 2*nlo + parity; lane col0 of C owns adjacent
// channels (2*col0, 2*col0+1); k index == raw input channel (dword q = chans 2q,2q+1).
__global__ void wavenet_prep(const float* __restrict__ wt, const float* __restrict__ wsg,
                             const float* __restrict__ wsk, const float* __restrict__ wfin,
                             unsigned* __restrict__ out)
{
    int id = blockIdx.x * 256 + threadIdx.x;
    if (id >= PREP_TOT) return;
    if (id >= PREP_N) { out[id] = 0u; return; }   // zero logits + counter
    int dw = id & 3, lane = (id >> 2) & 63;
    int g = lane >> 4, nlo = lane & 15;
    int k0 = g * 8 + dw * 2, k1 = k0 + 1;
    float v0, v1;
    if (id < WS_SKIP) {
        int nt = (id >> 8) & 3; int q = id >> 10;
        int tap = q % 3, i = q / 3;
        int chan = 2 * nlo + (nt & 1);
        const float* src = (nt < 2) ? wt : wsg;
        v0 = src[((i * 3 + tap) * 32 + k0) * 32 + chan];
        v1 = src[((i * 3 + tap) * 32 + k1) * 32 + chan];
    } else if (id < WS_FIN) {
        int t = id - WS_SKIP;
        int nt = (t >> 8) & 1; int i = t >> 9;
        int chan = 2 * nlo + nt;
        v0 = wsk[(i * 32 + k0) * 32 + chan];
        v1 = wsk[(i * 32 + k1) * 32 + chan];
    } else {
        int t = id - WS_FIN;
        int nt = (t >> 8) & 1;
        int chan = 2 * nlo + nt;
        v0 = wfin[k0 * 32 + chan];
        v1 = wfin[k1 * 32 + chan];
    }
    out[id] = packh(v0, v1);
}

// ---------------- main fused kernel ----------------
__global__ __launch_bounds__(NTHR, 3)
void wavenet_main(const float* __restrict__ x,
                  const float* __restrict__ w_init, const float* __restrict__ b_init,
                  const float* __restrict__ b_tanh, const float* __restrict__ b_sig,
                  const float* __restrict__ b_skip, const float* __restrict__ b_final,
                  const float* __restrict__ b_dense,
                  const float* __restrict__ w_dense,
                  const unsigned* __restrict__ wsB,
                  float* __restrict__ logits, unsigned* __restrict__ counter,
                  float* __restrict__ out)
{
    __shared__ unsigned h_pack[2 * HBUF];      // double-buffered, 55296 B
    __shared__ unsigned z_pack[6 * 16 * HS];   // 6912 B
    __shared__ float x_s[NTHR];                // 1536 B
    __shared__ float red[6][2];

    const int tid  = threadIdx.x;
    const int lane = tid & 63;
    const int wv   = tid >> 6;
    const int tile = blockIdx.x & (NTILES - 1);
    const int b    = blockIdx.x >> 6;
    const int col0 = lane & 15;
    const int g4   = lane >> 4;

    const float wi0 = w_init[2 * col0], wi1 = w_init[2 * col0 + 1];
    const float bi0 = b_init[2 * col0], bi1 = b_init[2 * col0 + 1];

    // ---- init conv (CIN=1) -> f16 h in buf0 ----
    {
        int j = tid;
        int tg = tile * TILE - HALO + j;
        bool valid = (tg >= 0) && (tg < T_LEN);
        float xv = valid ? x[(size_t)b * T_LEN + tg] : 0.0f;
        x_s[j] = xv;
        unsigned* hp = &h_pack[j * HS];
        #pragma unroll
        for (int q = 0; q < 8; ++q) {
            float f0 = relu(fmaf(xv, w_init[4 * q],     b_init[4 * q]));
            float f1 = relu(fmaf(xv, w_init[4 * q + 1], b_init[4 * q + 1]));
            float f2 = relu(fmaf(xv, w_init[4 * q + 2], b_init[4 * q + 2]));
            float f3 = relu(fmaf(xv, w_init[4 * q + 3], b_init[4 * q + 3]));
            uint2 pk;
            pk.x = valid ? packh(f0, f1) : 0u;
            pk.y = valid ? packh(f2, f3) : 0u;
            *(uint2*)(hp + 2 * q) = pk;
        }
    }

    unsigned* zb = &z_pack[wv * 16 * HS];

    for (int i = 0; i < NBLK; ++i) {
        const int d = 1 << i;
        __syncthreads();   // init / prev iter's h writes visible
        const unsigned* cur = &h_pack[(i & 1) * HBUF];
        unsigned*       nxt = &h_pack[((i + 1) & 1) * HBUF];

        f32x4 acc[4][4];
        #pragma unroll
        for (int mt = 0; mt < 4; ++mt)
            #pragma unroll
            for (int nt = 0; nt < 4; ++nt) acc[mt][nt] = (f32x4){0.f, 0.f, 0.f, 0.f};

        // conv GEMM: [384 x 96] x [96 x 64], single-product f16
        #pragma unroll
        for (int tap = 0; tap < 3; ++tap) {
            half8 bw[4];
            #pragma unroll
            for (int nt = 0; nt < 4; ++nt)
                bw[nt] = *(const half8*)(wsB + (((i * 3 + tap) * 4 + nt)) * 256 + lane * 4);
            int rb = wv * 64 + (tap - 1) * d + col0;
            #pragma unroll
            for (int mt = 0; mt < 4; ++mt) {
                int r = rb + 16 * mt;
                r = r < 0 ? 0 : (r > NTHR - 1 ? NTHR - 1 : r);
                const unsigned* hp = cur + r * HS + g4 * 4;
                AFR a; a.u2[0] = *(const uint2*)hp; a.u2[1] = *(const uint2*)(hp + 2);
                #pragma unroll
                for (int nt = 0; nt < 4; ++nt)
                    acc[mt][nt] = MFMA(a.v, bw[nt], acc[mt][nt]);
            }
        }

        // epilogue (no barrier: z is wave-local, h writes go to nxt)
        half8 skw[2];
        #pragma unroll
        for (int nt = 0; nt < 2; ++nt)
            skw[nt] = *(const half8*)(wsB + WS_SKIP + (i * 2 + nt) * 256 + lane * 4);
        float2 btv = *(const float2*)&b_tanh[i * 32 + 2 * col0];
        float2 bsv = *(const float2*)&b_sig [i * 32 + 2 * col0];
        float2 bkv = *(const float2*)&b_skip[i * 32 + 2 * col0];

        #pragma unroll
        for (int mt = 0; mt < 4; ++mt) {
            // gated activation -> z into wave-local LDS (C-layout -> A-layout transpose)
            #pragma unroll
            for (int reg = 0; reg < 4; ++reg) {
                float z0 = tanh_fast(acc[mt][0][reg] + btv.x) * sig_fast(acc[mt][2][reg] + bsv.x);
                float z1 = tanh_fast(acc[mt][1][reg] + btv.y) * sig_fast(acc[mt][3][reg] + bsv.y);
                zb[(4 * g4 + reg) * HS + col0] = packh(z0, z1);
            }
            asm volatile("s_waitcnt lgkmcnt(0)" ::: "memory");
            const unsigned* za = zb + col0 * HS + g4 * 4;
            AFR az; az.u2[0] = *(const uint2*)za; az.u2[1] = *(const uint2*)(za + 2);
            f32x4 s0 = (f32x4){0.f, 0.f, 0.f, 0.f}, s1 = (f32x4){0.f, 0.f, 0.f, 0.f};
            s0 = MFMA(az.v, skw[0], s0);
            s1 = MFMA(az.v, skw[1], s1);
            // skip epilogue + residual (telescope: skip_sum = h6 - h0)
            #pragma unroll
            for (int reg = 0; reg < 4; ++reg) {
                int row = wv * 64 + 16 * mt + 4 * g4 + reg;
                int tgr = tile * TILE - HALO + row;
                bool vr = (tgr >= 0) && (tgr < T_LEN);
                float sk0 = relu(s0[reg] + bkv.x);
                float sk1 = relu(s1[reg] + bkv.y);
                unsigned ph = cur[row * HS + col0];
                float h0n = sk0 + f16a(ph);
                float h1n = sk1 + f16b(ph);
                unsigned pk;
                if (i != NBLK - 1) {
                    pk = vr ? packh(h0n, h1n) : 0u;
                } else {
                    float xr  = x_s[row];
                    float hi0 = relu(fmaf(xr, wi0, bi0));
                    float hi1 = relu(fmaf(xr, wi1, bi1));
                    pk = packh(relu(h0n - hi0), relu(h1n - hi1));
                }
                nxt[row * HS + col0] = pk;
            }
        }
    }

    // ---- final 1x1 conv via MFMA on y (own-wave rows; in-order DS, drain first) ----
    asm volatile("s_waitcnt lgkmcnt(0)" ::: "memory");
    const unsigned* ybuf = &h_pack[(NBLK & 1) * HBUF];
    half8 fw[2];
    #pragma unroll
    for (int nt = 0; nt < 2; ++nt)
        fw[nt] = *(const half8*)(wsB + WS_FIN + nt * 256 + lane * 4);
    float2 bfv = *(const float2*)&b_final[2 * col0];
    float pa = 0.0f, pb = 0.0f;

    #pragma unroll
    for (int mt = 0; mt < 4; ++mt) {
        const unsigned* ya = ybuf + (wv * 64 + 16 * mt + col0) * HS + g4 * 4;
        AFR ay; ay.u2[0] = *(const uint2*)ya; ay.u2[1] = *(const uint2*)(ya + 2);
        f32x4 f0 = (f32x4){0.f, 0.f, 0.f, 0.f}, f1 = (f32x4){0.f, 0.f, 0.f, 0.f};
        f0 = MFMA(ay.v, fw[0], f0);
        f1 = MFMA(ay.v, fw[1], f1);
        #pragma unroll
        for (int reg = 0; reg < 4; ++reg) {
            int row = wv * 64 + 16 * mt + 4 * g4 + reg;
            if (row >= HALO && row < HALO + TILE) {
                int tgr = tile * TILE - HALO + row;
                float v0 = relu(f0[reg] + bfv.x);
                float v1 = relu(f1[reg] + bfv.y);
                float4 wd = *(const float4*)&w_dense[((size_t)tgr * 32 + 2 * col0) * 2];
                pa = fmaf(v0, wd.x, pa); pb = fmaf(v0, wd.y, pb);
                pa = fmaf(v1, wd.z, pa); pb = fmaf(v1, wd.w, pb);
            }
        }
    }

    // block reduction -> logits; last-arriving block does the softmax
    #pragma unroll
    for (int off = 32; off > 0; off >>= 1) {
        pa += __shfl_down(pa, off);
        pb += __shfl_down(pb, off);
    }
    if (lane == 0) { red[wv][0] = pa; red[wv][1] = pb; }
    __syncthreads();
    if (tid == 0) {
        float s0 = 0.0f, s1 = 0.0f;
        #pragma unroll
        for (int w = 0; w < 6; ++w) { s0 += red[w][0]; s1 += red[w][1]; }
        atomicAdd(&logits[b * 2 + 0], s0);
        atomicAdd(&logits[b * 2 + 1], s1);
        __threadfence();
        unsigned arrived = atomicAdd(counter, 1u);
        if (arrived == (unsigned)(NBATCH * NTILES - 1)) {
            __threadfence();
            float bd0 = b_dense[0], bd1 = b_dense[1];
            for (int bb = 0; bb < NBATCH; ++bb) {
                float l0 = atomicAdd(&logits[bb * 2 + 0], 0.0f) + bd0;
                float l1 = atomicAdd(&logits[bb * 2 + 1], 0.0f) + bd1;
                float m  = fmaxf(l0, l1);
                float e0 = __expf(l0 - m), e1 = __expf(l1 - m);
                float inv = __builtin_amdgcn_rcpf(e0 + e1);
                out[bb * 2 + 0] = e0 * inv;
                out[bb * 2 + 1] = e1 * inv;
            }
        }
    }
}

extern "C" void kernel_launch(void* const* d_in, const int* in_sizes, int n_in,
                              void* d_out, int out_size, void* d_ws, size_t ws_size,
                              hipStream_t stream) {
    const float* x       = (const float*)d_in[0];
    const float* w_init  = (const float*)d_in[1];
    const float* b_init  = (const float*)d_in[2];
    const float* w_tanh  = (const float*)d_in[3];
    const float* b_tanh  = (const float*)d_in[4];
    const float* w_sig   = (const float*)d_in[5];
    const float* b_sig   = (const float*)d_in[6];
    const float* w_skip  = (const float*)d_in[7];
    const float* b_skip  = (const float*)d_in[8];
    const float* w_final = (const float*)d_in[9];
    const float* b_final = (const float*)d_in[10];
    const float* w_dense = (const float*)d_in[11];
    const float* b_dense = (const float*)d_in[12];

    unsigned* wsB     = (unsigned*)d_ws;
    float*    logits  = (float*)d_ws + WS_LOG;
    unsigned* counter = (unsigned*)d_ws + WS_CNT;

    wavenet_prep<<<(PREP_TOT + 255) / 256, 256, 0, stream>>>(w_tanh, w_sig, w_skip, w_final, wsB);
    wavenet_main<<<NBATCH * NTILES, NTHR, 0, stream>>>(
        x, w_init, b_init, b_tanh, b_sig, b_skip, b_final, b_dense, w_dense,
        wsB, logits, counter, (float*)d_out);
}

// Round 8
// 159.121 us; speedup vs baseline: 1.5108x; 1.0538x over previous
//
#include <hip/hip_runtime.h>
#include <math.h>

#define T_LEN   16384
#define NBATCH  8
#define NBLK    6
#define TILE    256
#define HALO    63
#define NTHR    384
#define NTILES  64
#define HS      18            // f16 row stride in dwords (72 B)
#define HBUF    (NTHR * HS)   // one h buffer in dwords

// workspace layout (dwords)
#define WS_CONV 0             // [i6][tap3][nt4][lane64][dw4] = 18432
#define WS_SKIP 18432         // [i6][nt2][lane64][dw4]      = 3072
#define WS_FIN  21504         // [nt2][lane64][dw4]          = 512
#define WS_LOG  22016         // 16 floats logits
#define WS_CNT  22032         // 1 uint completion counter
#define PREP_N  22016
#define PREP_TOT 22036

typedef _Float16 half8 __attribute__((ext_vector_type(8)));
typedef __fp16  fp16x2 __attribute__((ext_vector_type(2)));
typedef float f32x4  __attribute__((ext_vector_type(4)));

union HPK { unsigned u; _Float16 h[2]; fp16x2 pk; };
union AFR { uint2 u2[2]; half8 v; };

__device__ __forceinline__ unsigned packh(float a, float b) {   // 1x v_cvt_pkrtz_f16_f32
    HPK r; r.pk = __builtin_amdgcn_cvt_pkrtz(a, b); return r.u;
}
__device__ __forceinline__ float f16a(unsigned p) { HPK r; r.u = p; return (float)r.h[0]; }
__device__ __forceinline__ float f16b(unsigned p) { HPK r; r.u = p; return (float)r.h[1]; }

// tanh(a)*sigmoid(b), overflow-safe, 3 quarter-rate ops (2 exp + 1 rcp)
__device__ __forceinline__ float gated(float a, float b) {
    float ea  = __expf(-2.0f * fabsf(a));      // (0,1]
    float fb  = __expf(-b);
    float num = 1.0f - ea;
    float den = (1.0f + ea) * (1.0f + fb);
    float t   = num * __builtin_amdgcn_rcpf(den);
    return __builtin_copysignf(t, a);
}
__device__ __forceinline__ float relu(float x) { return fmaxf(x, 0.0f); }

#define MFMA(a, b, c) __builtin_amdgcn_mfma_f32_16x16x32_f16((a), (b), (c), 0, 0, 0)

// ---------------- weight prep: fp32 -> f16 B-fragments (permuted cols) ----------------
// matrix col n = nt*16+nlo holds channel 2*nlo + parity; lane col0 of C owns adjacent
// channels (2*col0, 2*col0+1); k index == raw input channel.
__global__ void wavenet_prep(const float* __restrict__ wt, const float* __restrict__ wsg,
                             const float* __restrict__ wsk, const float* __restrict__ wfin,
                             unsigned* __restrict__ out)
{
    int id = blockIdx.x * 256 + threadIdx.x;
    if (id >= PREP_TOT) return;
    if (id >= PREP_N) { out[id] = 0u; return; }   // zero logits + counter
    int dw = id & 3, lane = (id >> 2) & 63;
    int g = lane >> 4, nlo = lane & 15;
    int k0 = g * 8 + dw * 2, k1 = k0 + 1;
    float v0, v1;
    if (id < WS_SKIP) {
        int nt = (id >> 8) & 3; int q = id >> 10;
        int tap = q % 3, i = q / 3;
        int chan = 2 * nlo + (nt & 1);
        const float* src = (nt < 2) ? wt : wsg;
        v0 = src[((i * 3 + tap) * 32 + k0) * 32 + chan];
        v1 = src[((i * 3 + tap) * 32 + k1) * 32 + chan];
    } else if (id < WS_FIN) {
        int t = id - WS_SKIP;
        int nt = (t >> 8) & 1; int i = t >> 9;
        int chan = 2 * nlo + nt;
        v0 = wsk[(i * 32 + k0) * 32 + chan];
        v1 = wsk[(i * 32 + k1) * 32 + chan];
    } else {
        int t = id - WS_FIN;
        int nt = (t >> 8) & 1;
        int chan = 2 * nlo + nt;
        v0 = wfin[k0 * 32 + chan];
        v1 = wfin[k1 * 32 + chan];
    }
    HPK r; r.h[0] = (_Float16)v0; r.h[1] = (_Float16)v1;   // RNE for weights
    out[id] = r.u;
}

// ---------------- main fused kernel ----------------
__global__ __launch_bounds__(NTHR, 3)
void wavenet_main(const float* __restrict__ x,
                  const float* __restrict__ w_init, const float* __restrict__ b_init,
                  const float* __restrict__ b_tanh, const float* __restrict__ b_sig,
                  const float* __restrict__ b_skip, const float* __restrict__ b_final,
                  const float* __restrict__ b_dense,
                  const float* __restrict__ w_dense,
                  const unsigned* __restrict__ wsB,
                  float* __restrict__ logits, unsigned* __restrict__ counter,
                  float* __restrict__ out)
{
    __shared__ unsigned h_pack[2 * HBUF];      // double-buffered, 55296 B
    __shared__ unsigned z_pack[6 * 32 * HS];   // 32 rows/wave, 13824 B
    __shared__ float x_s[NTHR];                // 1536 B
    __shared__ float red[6][2];

    const int tid  = threadIdx.x;
    const int lane = tid & 63;
    const int wv   = tid >> 6;
    const int tile = blockIdx.x & (NTILES - 1);
    const int b    = blockIdx.x >> 6;
    const int col0 = lane & 15;
    const int g4   = lane >> 4;

    const float wi0 = w_init[2 * col0], wi1 = w_init[2 * col0 + 1];
    const float bi0 = b_init[2 * col0], bi1 = b_init[2 * col0 + 1];

    // ---- init conv (CIN=1) -> f16 h in buf0 ----
    {
        int j = tid;
        int tg = tile * TILE - HALO + j;
        bool valid = (tg >= 0) && (tg < T_LEN);
        float xv = valid ? x[(size_t)b * T_LEN + tg] : 0.0f;
        x_s[j] = xv;
        unsigned* hp = &h_pack[j * HS];
        #pragma unroll
        for (int q = 0; q < 8; ++q) {
            float f0 = relu(fmaf(xv, w_init[4 * q],     b_init[4 * q]));
            float f1 = relu(fmaf(xv, w_init[4 * q + 1], b_init[4 * q + 1]));
            float f2 = relu(fmaf(xv, w_init[4 * q + 2], b_init[4 * q + 2]));
            float f3 = relu(fmaf(xv, w_init[4 * q + 3], b_init[4 * q + 3]));
            uint2 pk;
            pk.x = valid ? packh(f0, f1) : 0u;
            pk.y = valid ? packh(f2, f3) : 0u;
            *(uint2*)(hp + 2 * q) = pk;
        }
    }
    __syncthreads();

    // own residual rows live in registers (packed f16 pairs)
    unsigned h_own[4][4];
    #pragma unroll
    for (int m = 0; m < 4; ++m)
        #pragma unroll
        for (int reg = 0; reg < 4; ++reg)
            h_own[m][reg] = h_pack[(wv * 64 + 16 * m + 4 * g4 + reg) * HS + col0];

    unsigned* zb = &z_pack[wv * 32 * HS];

    #pragma unroll
    for (int i = 0; i < NBLK; ++i) {
        const int d = 1 << i;
        const unsigned* cur = &h_pack[(i & 1) * HBUF];
        unsigned*       nxt = &h_pack[((i + 1) & 1) * HBUF];

        // all weight/bias loads for this iter issued up front (overlap conv)
        half8 skw[2];
        #pragma unroll
        for (int nt = 0; nt < 2; ++nt)
            skw[nt] = *(const half8*)(wsB + WS_SKIP + (i * 2 + nt) * 256 + lane * 4);
        float2 btv = *(const float2*)&b_tanh[i * 32 + 2 * col0];
        float2 bsv = *(const float2*)&b_sig [i * 32 + 2 * col0];
        float2 bkv = *(const float2*)&b_skip[i * 32 + 2 * col0];

        f32x4 acc[4][4];
        #pragma unroll
        for (int mt = 0; mt < 4; ++mt)
            #pragma unroll
            for (int nt = 0; nt < 4; ++nt) acc[mt][nt] = (f32x4){0.f, 0.f, 0.f, 0.f};

        // conv GEMM: [384 x 96] x [96 x 64], single-product f16
        #pragma unroll
        for (int tap = 0; tap < 3; ++tap) {
            half8 bw[4];
            #pragma unroll
            for (int nt = 0; nt < 4; ++nt)
                bw[nt] = *(const half8*)(wsB + (((i * 3 + tap) * 4 + nt)) * 256 + lane * 4);
            int rb = wv * 64 + (tap - 1) * d + col0;
            #pragma unroll
            for (int mt = 0; mt < 4; ++mt) {
                int r = rb + 16 * mt;
                r = r < 0 ? 0 : (r > NTHR - 1 ? NTHR - 1 : r);
                const unsigned* hp = cur + r * HS + g4 * 4;
                AFR a; a.u2[0] = *(const uint2*)hp; a.u2[1] = *(const uint2*)(hp + 2);
                #pragma unroll
                for (int nt = 0; nt < 4; ++nt)
                    acc[mt][nt] = MFMA(a.v, bw[nt], acc[mt][nt]);
            }
        }

        // epilogue in mt-pairs: both members' gate VALU + z writes, ONE wait, then MFMAs
        #pragma unroll
        for (int p = 0; p < 2; ++p) {
            #pragma unroll
            for (int q = 0; q < 2; ++q) {
                const int m = 2 * p + q;
                #pragma unroll
                for (int reg = 0; reg < 4; ++reg) {
                    float z0 = gated(acc[m][0][reg] + btv.x, acc[m][2][reg] + bsv.x);
                    float z1 = gated(acc[m][1][reg] + btv.y, acc[m][3][reg] + bsv.y);
                    zb[(q * 16 + 4 * g4 + reg) * HS + col0] = packh(z0, z1);
                }
            }
            asm volatile("s_waitcnt lgkmcnt(0)" ::: "memory");
            #pragma unroll
            for (int q = 0; q < 2; ++q) {
                const int m = 2 * p + q;
                const unsigned* za = zb + (q * 16 + col0) * HS + g4 * 4;
                AFR az; az.u2[0] = *(const uint2*)za; az.u2[1] = *(const uint2*)(za + 2);
                f32x4 s0 = (f32x4){0.f, 0.f, 0.f, 0.f}, s1 = (f32x4){0.f, 0.f, 0.f, 0.f};
                s0 = MFMA(az.v, skw[0], s0);
                s1 = MFMA(az.v, skw[1], s1);
                #pragma unroll
                for (int reg = 0; reg < 4; ++reg) {
                    const int row = wv * 64 + 16 * m + 4 * g4 + reg;
                    float sk0 = relu(s0[reg] + bkv.x);
                    float sk1 = relu(s1[reg] + bkv.y);
                    unsigned ph = h_own[m][reg];
                    float h0n = sk0 + f16a(ph);
                    float h1n = sk1 + f16b(ph);
                    unsigned pk;
                    if (i != NBLK - 1) {
                        int tgr = tile * TILE - HALO + row;
                        bool vr = (tgr >= 0) && (tgr < T_LEN);
                        pk = vr ? packh(h0n, h1n) : 0u;
                    } else {
                        // y = relu(skip_sum) = relu(h6 - h0), h0 recomputed from x
                        float xr  = x_s[row];
                        float hi0 = relu(fmaf(xr, wi0, bi0));
                        float hi1 = relu(fmaf(xr, wi1, bi1));
                        pk = packh(relu(h0n - hi0), relu(h1n - hi1));
                    }
                    h_own[m][reg] = pk;
                    nxt[row * HS + col0] = pk;
                }
            }
        }
        __syncthreads();   // h writes visible for next iter's conv (last one: final phase)
    }

    // ---- final 1x1 conv via MFMA on y (buf0; barrier above already drained) ----
    const unsigned* ybuf = &h_pack[(NBLK & 1) * HBUF];
    half8 fw[2];
    #pragma unroll
    for (int nt = 0; nt < 2; ++nt)
        fw[nt] = *(const half8*)(wsB + WS_FIN + nt * 256 + lane * 4);
    float2 bfv = *(const float2*)&b_final[2 * col0];
    float pa = 0.0f, pb = 0.0f;

    #pragma unroll
    for (int mt = 0; mt < 4; ++mt) {
        const unsigned* ya = ybuf + (wv * 64 + 16 * mt + col0) * HS + g4 * 4;
        AFR ay; ay.u2[0] = *(const uint2*)ya; ay.u2[1] = *(const uint2*)(ya + 2);
        f32x4 f0 = (f32x4){0.f, 0.f, 0.f, 0.f}, f1 = (f32x4){0.f, 0.f, 0.f, 0.f};
        f0 = MFMA(ay.v, fw[0], f0);
        f1 = MFMA(ay.v, fw[1], f1);
        #pragma unroll
        for (int reg = 0; reg < 4; ++reg) {
            int row = wv * 64 + 16 * mt + 4 * g4 + reg;
            if (row >= HALO && row < HALO + TILE) {
                int tgr = tile * TILE - HALO + row;
                float v0 = relu(f0[reg] + bfv.x);
                float v1 = relu(f1[reg] + bfv.y);
                float4 wd = *(const float4*)&w_dense[((size_t)tgr * 32 + 2 * col0) * 2];
                pa = fmaf(v0, wd.x, pa); pb = fmaf(v0, wd.y, pb);
                pa = fmaf(v1, wd.z, pa); pb = fmaf(v1, wd.w, pb);
            }
        }
    }

    // block reduction -> logits; last-arriving block does the softmax
    #pragma unroll
    for (int off = 32; off > 0; off >>= 1) {
        pa += __shfl_down(pa, off);
        pb += __shfl_down(pb, off);
    }
    if (lane == 0) { red[wv][0] = pa; red[wv][1] = pb; }
    __syncthreads();
    if (tid == 0) {
        float s0 = 0.0f, s1 = 0.0f;
        #pragma unroll
        for (int w = 0; w < 6; ++w) { s0 += red[w][0]; s1 += red[w][1]; }
        atomicAdd(&logits[b * 2 + 0], s0);
        atomicAdd(&logits[b * 2 + 1], s1);
        __threadfence();
        unsigned arrived = atomicAdd(counter, 1u);
        if (arrived == (unsigned)(NBATCH * NTILES - 1)) {
            __threadfence();
            float bd0 = b_dense[0], bd1 = b_dense[1];
            for (int bb = 0; bb < NBATCH; ++bb) {
                float l0 = atomicAdd(&logits[bb * 2 + 0], 0.0f) + bd0;
                float l1 = atomicAdd(&logits[bb * 2 + 1], 0.0f) + bd1;
                float m  = fmaxf(l0, l1);
                float e0 = __expf(l0 - m), e1 = __expf(l1 - m);
                float inv = __builtin_amdgcn_rcpf(e0 + e1);
                out[bb * 2 + 0] = e0 * inv;
                out[bb * 2 + 1] = e1 * inv;
            }
        }
    }
}

extern "C" void kernel_launch(void* const* d_in, const int* in_sizes, int n_in,
                              void* d_out, int out_size, void* d_ws, size_t ws_size,
                              hipStream_t stream) {
    const float* x       = (const float*)d_in[0];
    const float* w_init  = (const float*)d_in[1];
    const float* b_init  = (const float*)d_in[2];
    const float* w_tanh  = (const float*)d_in[3];
    const float* b_tanh  = (const float*)d_in[4];
    const float* w_sig   = (const float*)d_in[5];
    const float* b_sig   = (const float*)d_in[6];
    const float* w_skip  = (const float*)d_in[7];
    const float* b_skip  = (const float*)d_in[8];
    const float* w_final = (const float*)d_in[9];
    const float* b_final = (const float*)d_in[10];
    const float* w_dense = (const float*)d_in[11];
    const float* b_dense = (const float*)d_in[12];

    unsigned* wsB     = (unsigned*)d_ws;
    float*    logits  = (float*)d_ws + WS_LOG;
    unsigned* counter = (unsigned*)d_ws + WS_CNT;

    wavenet_prep<<<(PREP_TOT + 255) / 256, 256, 0, stream>>>(w_tanh, w_sig, w_skip, w_final, wsB);
    wavenet_main<<<NBATCH * NTILES, NTHR, 0, stream>>>(
        x, w_init, b_init, b_tanh, b_sig, b_skip, b_final, b_dense, w_dense,
        wsB, logits, counter, (float*)d_out);
}

// Round 9
// 154.199 us; speedup vs baseline: 1.5591x; 1.0319x over previous
//
#include <hip/hip_runtime.h>
#include <math.h>

#define T_LEN   16384
#define NBATCH  8
#define NBLK    6
#define TILE    256
#define HALO    63
#define NTHR    384
#define NTILES  64
#define HS      18            // f16 row stride in dwords (72 B)
#define HBUF    (NTHR * HS)   // one h buffer in dwords

// workspace layout (dwords)
#define WS_CONV 0             // [i6][tap3][nt4][lane64][dw4] = 18432
#define WS_SKIP 18432         // [i6][nt2][lane64][dw4]      = 3072
#define WS_FIN  21504         // [nt2][lane64][dw4]          = 512
#define WS_LOG  22016         // 16 floats logits
#define WS_CNT  22032         // 1 uint completion counter
#define PREP_N  22016
#define PREP_TOT 22036

typedef _Float16 half8 __attribute__((ext_vector_type(8)));
typedef __fp16  fp16x2 __attribute__((ext_vector_type(2)));
typedef float f32x4  __attribute__((ext_vector_type(4)));

union HPK { unsigned u; _Float16 h[2]; fp16x2 pk; };
union AFR { uint2 u2[2]; half8 v; };

__device__ __forceinline__ unsigned packh(float a, float b) {   // 1x v_cvt_pkrtz_f16_f32
    HPK r; r.pk = __builtin_amdgcn_cvt_pkrtz(a, b); return r.u;
}
__device__ __forceinline__ float f16a(unsigned p) { HPK r; r.u = p; return (float)r.h[0]; }
__device__ __forceinline__ float f16b(unsigned p) { HPK r; r.u = p; return (float)r.h[1]; }

// tanh(a)*sigmoid(b), overflow-safe, 3 quarter-rate ops (2 exp + 1 rcp)
__device__ __forceinline__ float gated(float a, float b) {
    float ea  = __expf(-2.0f * fabsf(a));      // (0,1]
    float fb  = __expf(-b);
    float num = 1.0f - ea;
    float den = (1.0f + ea) * (1.0f + fb);
    float t   = num * __builtin_amdgcn_rcpf(den);
    return __builtin_copysignf(t, a);
}
__device__ __forceinline__ float relu(float x) { return fmaxf(x, 0.0f); }

#define MFMA(a, b, c) __builtin_amdgcn_mfma_f32_16x16x32_f16((a), (b), (c), 0, 0, 0)

// ---------------- weight prep: fp32 -> f16 B-fragments (permuted cols) ----------------
// matrix col n = nt*16+nlo holds channel 2*nlo + parity; lane col0 of C owns adjacent
// channels (2*col0, 2*col0+1); k index == raw input channel.
__global__ void wavenet_prep(const float* __restrict__ wt, const float* __restrict__ wsg,
                             const float* __restrict__ wsk, const float* __restrict__ wfin,
                             unsigned* __restrict__ out)
{
    int id = blockIdx.x * 256 + threadIdx.x;
    if (id >= PREP_TOT) return;
    if (id >= PREP_N) { out[id] = 0u; return; }   // zero logits + counter
    int dw = id & 3, lane = (id >> 2) & 63;
    int g = lane >> 4, nlo = lane & 15;
    int k0 = g * 8 + dw * 2, k1 = k0 + 1;
    float v0, v1;
    if (id < WS_SKIP) {
        int nt = (id >> 8) & 3; int q = id >> 10;
        int tap = q % 3, i = q / 3;
        int chan = 2 * nlo + (nt & 1);
        const float* src = (nt < 2) ? wt : wsg;
        v0 = src[((i * 3 + tap) * 32 + k0) * 32 + chan];
        v1 = src[((i * 3 + tap) * 32 + k1) * 32 + chan];
    } else if (id < WS_FIN) {
        int t = id - WS_SKIP;
        int nt = (t >> 8) & 1; int i = t >> 9;
        int chan = 2 * nlo + nt;
        v0 = wsk[(i * 32 + k0) * 32 + chan];
        v1 = wsk[(i * 32 + k1) * 32 + chan];
    } else {
        int t = id - WS_FIN;
        int nt = (t >> 8) & 1;
        int chan = 2 * nlo + nt;
        v0 = wfin[k0 * 32 + chan];
        v1 = wfin[k1 * 32 + chan];
    }
    HPK r; r.h[0] = (_Float16)v0; r.h[1] = (_Float16)v1;   // RNE for weights
    out[id] = r.u;
}

// ---------------- main fused kernel ----------------
__global__ __launch_bounds__(NTHR, 3)
void wavenet_main(const float* __restrict__ x,
                  const float* __restrict__ w_init, const float* __restrict__ b_init,
                  const float* __restrict__ b_tanh, const float* __restrict__ b_sig,
                  const float* __restrict__ b_skip, const float* __restrict__ b_final,
                  const float* __restrict__ b_dense,
                  const float* __restrict__ w_dense,
                  const unsigned* __restrict__ wsB,
                  float* __restrict__ logits, unsigned* __restrict__ counter,
                  float* __restrict__ out)
{
    __shared__ unsigned h_pack[2 * HBUF];      // double-buffered, 55296 B
    __shared__ unsigned z_pack[6 * 32 * HS];   // 32 rows/wave, 13824 B
    __shared__ float x_s[NTHR];                // 1536 B
    __shared__ float red[6][2];

    const int tid  = threadIdx.x;
    const int lane = tid & 63;
    const int wv   = tid >> 6;
    const int tile = blockIdx.x & (NTILES - 1);
    const int b    = blockIdx.x >> 6;
    const int col0 = lane & 15;
    const int g4   = lane >> 4;

    const float wi0 = w_init[2 * col0], wi1 = w_init[2 * col0 + 1];
    const float bi0 = b_init[2 * col0], bi1 = b_init[2 * col0 + 1];

    // ---- init conv (CIN=1) -> f16 h in buf0 ----
    {
        int j = tid;
        int tg = tile * TILE - HALO + j;
        bool valid = (tg >= 0) && (tg < T_LEN);
        float xv = valid ? x[(size_t)b * T_LEN + tg] : 0.0f;
        x_s[j] = xv;
        unsigned* hp = &h_pack[j * HS];
        #pragma unroll
        for (int q = 0; q < 8; ++q) {
            float f0 = relu(fmaf(xv, w_init[4 * q],     b_init[4 * q]));
            float f1 = relu(fmaf(xv, w_init[4 * q + 1], b_init[4 * q + 1]));
            float f2 = relu(fmaf(xv, w_init[4 * q + 2], b_init[4 * q + 2]));
            float f3 = relu(fmaf(xv, w_init[4 * q + 3], b_init[4 * q + 3]));
            uint2 pk;
            pk.x = valid ? packh(f0, f1) : 0u;
            pk.y = valid ? packh(f2, f3) : 0u;
            *(uint2*)(hp + 2 * q) = pk;
        }
    }
    __syncthreads();

    unsigned* zb = &z_pack[wv * 32 * HS];

    #pragma unroll
    for (int i = 0; i < NBLK; ++i) {
        const int d = 1 << i;
        const unsigned* cur = &h_pack[(i & 1) * HBUF];
        unsigned*       nxt = &h_pack[((i + 1) & 1) * HBUF];

        // all weight/bias loads for this iter issued up front (overlap conv)
        half8 skw[2];
        #pragma unroll
        for (int nt = 0; nt < 2; ++nt)
            skw[nt] = *(const half8*)(wsB + WS_SKIP + (i * 2 + nt) * 256 + lane * 4);
        float2 btv = *(const float2*)&b_tanh[i * 32 + 2 * col0];
        float2 bsv = *(const float2*)&b_sig [i * 32 + 2 * col0];
        float2 bkv = *(const float2*)&b_skip[i * 32 + 2 * col0];

        f32x4 acc[4][4];
        #pragma unroll
        for (int mt = 0; mt < 4; ++mt)
            #pragma unroll
            for (int nt = 0; nt < 4; ++nt) acc[mt][nt] = (f32x4){0.f, 0.f, 0.f, 0.f};

        // conv GEMM: [384 x 96] x [96 x 64], single-product f16
        #pragma unroll
        for (int tap = 0; tap < 3; ++tap) {
            half8 bw[4];
            #pragma unroll
            for (int nt = 0; nt < 4; ++nt)
                bw[nt] = *(const half8*)(wsB + (((i * 3 + tap) * 4 + nt)) * 256 + lane * 4);
            int rb = wv * 64 + (tap - 1) * d + col0;
            #pragma unroll
            for (int mt = 0; mt < 4; ++mt) {
                int r = rb + 16 * mt;
                r = r < 0 ? 0 : (r > NTHR - 1 ? NTHR - 1 : r);
                const unsigned* hp = cur + r * HS + g4 * 4;
                AFR a; a.u2[0] = *(const uint2*)hp; a.u2[1] = *(const uint2*)(hp + 2);
                #pragma unroll
                for (int nt = 0; nt < 4; ++nt)
                    acc[mt][nt] = MFMA(a.v, bw[nt], acc[mt][nt]);
            }
        }

        // epilogue in mt-pairs: own-row h reads issued early (hide under gate VALU),
        // both members' gate VALU + z writes, ONE wait, then MFMAs + h update.
        #pragma unroll
        for (int p = 0; p < 2; ++p) {
            unsigned hold[2][4];
            #pragma unroll
            for (int q = 0; q < 2; ++q) {
                const int m = 2 * p + q;
                #pragma unroll
                for (int reg = 0; reg < 4; ++reg)
                    hold[q][reg] = cur[(wv * 64 + 16 * m + 4 * g4 + reg) * HS + col0];
                #pragma unroll
                for (int reg = 0; reg < 4; ++reg) {
                    float z0 = gated(acc[m][0][reg] + btv.x, acc[m][2][reg] + bsv.x);
                    float z1 = gated(acc[m][1][reg] + btv.y, acc[m][3][reg] + bsv.y);
                    zb[(q * 16 + 4 * g4 + reg) * HS + col0] = packh(z0, z1);
                }
            }
            asm volatile("s_waitcnt lgkmcnt(0)" ::: "memory");
            #pragma unroll
            for (int q = 0; q < 2; ++q) {
                const int m = 2 * p + q;
                const unsigned* za = zb + (q * 16 + col0) * HS + g4 * 4;
                AFR az; az.u2[0] = *(const uint2*)za; az.u2[1] = *(const uint2*)(za + 2);
                f32x4 s0 = (f32x4){0.f, 0.f, 0.f, 0.f}, s1 = (f32x4){0.f, 0.f, 0.f, 0.f};
                s0 = MFMA(az.v, skw[0], s0);
                s1 = MFMA(az.v, skw[1], s1);
                #pragma unroll
                for (int reg = 0; reg < 4; ++reg) {
                    const int row = wv * 64 + 16 * m + 4 * g4 + reg;
                    float sk0 = relu(s0[reg] + bkv.x);
                    float sk1 = relu(s1[reg] + bkv.y);
                    unsigned ph = hold[q][reg];
                    float h0n = sk0 + f16a(ph);
                    float h1n = sk1 + f16b(ph);
                    unsigned pk;
                    if (i != NBLK - 1) {
                        int tgr = tile * TILE - HALO + row;
                        bool vr = (tgr >= 0) && (tgr < T_LEN);
                        pk = vr ? packh(h0n, h1n) : 0u;
                    } else {
                        // y = relu(skip_sum) = relu(h6 - h0), h0 recomputed from x
                        float xr  = x_s[row];
                        float hi0 = relu(fmaf(xr, wi0, bi0));
                        float hi1 = relu(fmaf(xr, wi1, bi1));
                        pk = packh(relu(h0n - hi0), relu(h1n - hi1));
                    }
                    nxt[row * HS + col0] = pk;
                }
            }
        }
        __syncthreads();   // h writes visible for next iter's conv (last one: final phase)
    }

    // ---- final 1x1 conv via MFMA on y (buf0; barrier above already drained) ----
    const unsigned* ybuf = &h_pack[(NBLK & 1) * HBUF];
    half8 fw[2];
    #pragma unroll
    for (int nt = 0; nt < 2; ++nt)
        fw[nt] = *(const half8*)(wsB + WS_FIN + nt * 256 + lane * 4);
    float2 bfv = *(const float2*)&b_final[2 * col0];
    float pa = 0.0f, pb = 0.0f;

    #pragma unroll
    for (int mt = 0; mt < 4; ++mt) {
        const unsigned* ya = ybuf + (wv * 64 + 16 * mt + col0) * HS + g4 * 4;
        AFR ay; ay.u2[0] = *(const uint2*)ya; ay.u2[1] = *(const uint2*)(ya + 2);
        f32x4 f0 = (f32x4){0.f, 0.f, 0.f, 0.f}, f1 = (f32x4){0.f, 0.f, 0.f, 0.f};
        f0 = MFMA(ay.v, fw[0], f0);
        f1 = MFMA(ay.v, fw[1], f1);
        #pragma unroll
        for (int reg = 0; reg < 4; ++reg) {
            int row = wv * 64 + 16 * mt + 4 * g4 + reg;
            if (row >= HALO && row < HALO + TILE) {
                int tgr = tile * TILE - HALO + row;
                float v0 = relu(f0[reg] + bfv.x);
                float v1 = relu(f1[reg] + bfv.y);
                float4 wd = *(const float4*)&w_dense[((size_t)tgr * 32 + 2 * col0) * 2];
                pa = fmaf(v0, wd.x, pa); pb = fmaf(v0, wd.y, pb);
                pa = fmaf(v1, wd.z, pa); pb = fmaf(v1, wd.w, pb);
            }
        }
    }

    // block reduction -> logits; last-arriving block does the softmax
    #pragma unroll
    for (int off = 32; off > 0; off >>= 1) {
        pa += __shfl_down(pa, off);
        pb += __shfl_down(pb, off);
    }
    if (lane == 0) { red[wv][0] = pa; red[wv][1] = pb; }
    __syncthreads();
    if (tid == 0) {
        float s0 = 0.0f, s1 = 0.0f;
        #pragma unroll
        for (int w = 0; w < 6; ++w) { s0 += red[w][0]; s1 += red[w][1]; }
        atomicAdd(&logits[b * 2 + 0], s0);
        atomicAdd(&logits[b * 2 + 1], s1);
        __threadfence();
        unsigned arrived = atomicAdd(counter, 1u);
        if (arrived == (unsigned)(NBATCH * NTILES - 1)) {
            __threadfence();
            float bd0 = b_dense[0], bd1 = b_dense[1];
            for (int bb = 0; bb < NBATCH; ++bb) {
                float l0 = atomicAdd(&logits[bb * 2 + 0], 0.0f) + bd0;
                float l1 = atomicAdd(&logits[bb * 2 + 1], 0.0f) + bd1;
                float m  = fmaxf(l0, l1);
                float e0 = __expf(l0 - m), e1 = __expf(l1 - m);
                float inv = __builtin_amdgcn_rcpf(e0 + e1);
                out[bb * 2 + 0] = e0 * inv;
                out[bb * 2 + 1] = e1 * inv;
            }
        }
    }
}

extern "C" void kernel_launch(void* const* d_in, const int* in_sizes, int n_in,
                              void* d_out, int out_size, void* d_ws, size_t ws_size,
                              hipStream_t stream) {
    const float* x       = (const float*)d_in[0];
    const float* w_init  = (const float*)d_in[1];
    const float* b_init  = (const float*)d_in[2];
    const float* w_tanh  = (const float*)d_in[3];
    const float* b_tanh  = (const float*)d_in[4];
    const float* w_sig   = (const float*)d_in[5];
    const float* b_sig   = (const float*)d_in[6];
    const float* w_skip  = (const float*)d_in[7];
    const float* b_skip  = (const float*)d_in[8];
    const float* w_final = (const float*)d_in[9];
    const float* b_final = (const float*)d_in[10];
    const float* w_dense = (const float*)d_in[11];
    const float* b_dense = (const float*)d_in[12];

    unsigned* wsB     = (unsigned*)d_ws;
    float*    logits  = (float*)d_ws + WS_LOG;
    unsigned* counter = (unsigned*)d_ws + WS_CNT;

    wavenet_prep<<<(PREP_TOT + 255) / 256, 256, 0, stream>>>(w_tanh, w_sig, w_skip, w_final, wsB);
    wavenet_main<<<NBATCH * NTILES, NTHR, 0, stream>>>(
        x, w_init, b_init, b_tanh, b_sig, b_skip, b_final, b_dense, w_dense,
        wsB, logits, counter, (float*)d_out);
}